// Round 8
// baseline (85.826 us; speedup 1.0000x reference)
//
#include <hip/hip_runtime.h>

#if defined(__has_builtin)
#  if __has_builtin(__builtin_amdgcn_exp2f)
#    define EXP2F(x) __builtin_amdgcn_exp2f(x)
#  else
#    define EXP2F(x) exp2f(x)
#  endif
#else
#  define EXP2F(x) exp2f(x)
#endif

constexpr int NPIX  = 262144;
constexpr int NC    = 1024;
constexpr int NG    = 256;

// ---- DPP helpers (VALU pipe, no lgkm) ----
template <int CTRL>
__device__ __forceinline__ float dpp_add(float v) {
    union { float f; int i; } u, t;
    u.f = v;
    t.i = __builtin_amdgcn_update_dpp(0, u.i, CTRL, 0xF, 0xF, true);
    return v + t.f;
}
template <int CTRL>
__device__ __forceinline__ float dpp_mov(float v) {
    union { float f; int i; } u, t;
    u.f = v;
    t.i = __builtin_amdgcn_update_dpp(0, u.i, CTRL, 0xF, 0xF, true);
    return t.f;
}
__device__ __forceinline__ float sum16(float v) {
    v = dpp_add<0xB1>(v);   // quad_perm xor1
    v = dpp_add<0x4E>(v);   // quad_perm xor2
    v = dpp_add<0x141>(v);  // row_half_mirror (xor4 for sums)
    v = dpp_add<0x140>(v);  // row_mirror      (xor8 for sums)
    return v;               // all 16 lanes hold the group total
}

// ws layout: cx[NC] | cy[NC] | ca[NC] | pad to 4096 | sxy[NPIX] (float2)
constexpr int WS_SXY_OFF = 4096;   // floats

// prep: SoA center pack (ca = alpha * 2^{f|c|^2})
__global__ void prep_centers(const float* __restrict__ alphas,
                             const float* __restrict__ centers,
                             const float* __restrict__ sdp2p,
                             float* __restrict__ ws)
{
    const int c = blockIdx.x * blockDim.x + threadIdx.x;
    if (c < NC) {
        const float f  = -1.44269504088896340736f / (2.0f * sdp2p[0]);
        const float cx = centers[2 * c + 0];
        const float cy = centers[2 * c + 1];
        ws[c]          = cx;
        ws[NC + c]     = cy;
        ws[2 * NC + c] = alphas[c] * EXP2F(f * (cx * cx + cy * cy));
    }
}

// ---- kernel A: s = K @ betas, pure streaming. 32 rows per wave. ----
constexpr int BLOCKS_A = 2048;                 // 8192 waves x 32 rows = NPIX
__global__ __launch_bounds__(256, 4)
void deform_k(const float* __restrict__ betas,
              const float* __restrict__ K,
              float2* __restrict__ sxy)
{
    const int tid  = threadIdx.x;
    const int lane = tid & 63;
    const int wave = tid >> 6;
    const int l4   = lane & 15;
    const int lg   = lane >> 4;

    // betas fragments: lane covers cols 4*l4..+3 of each 64-col quarter
    const float4* bf4 = (const float4*)betas;
    float4 b0[4], b1[4];
    #pragma unroll
    for (int k = 0; k < 4; ++k) {
        b0[k] = bf4[l4 * 2 + k * 32];
        b1[k] = bf4[l4 * 2 + k * 32 + 1];
    }

    const int base = (blockIdx.x * 4 + wave) * 32;   // this wave's 32 rows

    #pragma unroll 2
    for (int it = 0; it < 8; ++it) {
        const float4* kr = (const float4*)(K + (size_t)(base + it * 4 + lg) * NG);
        float4 kv[4];
        #pragma unroll
        for (int k = 0; k < 4; ++k) kv[k] = kr[l4 + 16 * k];
        float sx = 0.f, sy = 0.f;
        #pragma unroll
        for (int k = 0; k < 4; ++k) {
            sx = fmaf(kv[k].x, b0[k].x, sx); sy = fmaf(kv[k].x, b0[k].y, sy);
            sx = fmaf(kv[k].y, b0[k].z, sx); sy = fmaf(kv[k].y, b0[k].w, sy);
            sx = fmaf(kv[k].z, b1[k].x, sx); sy = fmaf(kv[k].z, b1[k].y, sy);
            sx = fmaf(kv[k].w, b1[k].z, sx); sy = fmaf(kv[k].w, b1[k].w, sy);
        }
        sx = sum16(sx); sy = sum16(sy);
        if (l4 == it) sxy[base + it * 4 + lg] = make_float2(sx, sy);
    }
}

// ---- kernel B: RBF contraction, DPP-systolic over register-resident centers ----
__global__ __launch_bounds__(256, 4)
void rbf_k(const float* __restrict__ pixels,
           const float* __restrict__ sdp2p,
           const float* __restrict__ ws,
           float* __restrict__ out)
{
    const int tid  = threadIdx.x;
    const int lane = tid & 63;
    const int wave = tid >> 6;
    const int p    = blockIdx.x * 256 + wave * 64 + lane;

    const float f   = -1.44269504088896340736f / (2.0f * sdp2p[0]);
    const float m2f = -2.0f * f;

    // register-resident centers: lane holds c = lane*16 .. lane*16+15 (SoA)
    const float4* wcx4 = (const float4*)(ws);
    const float4* wcy4 = (const float4*)(ws + NC);
    const float4* wca4 = (const float4*)(ws + 2 * NC);
    float4 rcx[4], rcy[4], rca[4];
    #pragma unroll
    for (int j = 0; j < 4; ++j) {
        rcx[j] = wcx4[lane * 4 + j];
        rcy[j] = wcy4[lane * 4 + j];
        rca[j] = wca4[lane * 4 + j];
    }

    const float2 s  = ((const float2*)(ws + WS_SXY_OFF))[p];
    const float2 px = ((const float2*)pixels)[p];
    const float dx = px.x - s.x;
    const float dy = px.y - s.y;

    float dxs = m2f * dx, dys = m2f * dy, acc = 0.f;
    #pragma unroll 1
    for (int round = 0; round < 4; ++round) {
        #pragma unroll 2
        for (int t = 0; t < 16; ++t) {
            float t0 = 0.f, t1 = 0.f, t2 = 0.f, t3 = 0.f;
            #pragma unroll
            for (int j = 0; j < 4; ++j) {
                t0 = fmaf(rca[j].x, EXP2F(fmaf(dxs, rcx[j].x, dys * rcy[j].x)), t0);
                t1 = fmaf(rca[j].y, EXP2F(fmaf(dxs, rcx[j].y, dys * rcy[j].y)), t1);
                t2 = fmaf(rca[j].z, EXP2F(fmaf(dxs, rcx[j].z, dys * rcy[j].z)), t2);
                t3 = fmaf(rca[j].w, EXP2F(fmaf(dxs, rcx[j].w, dys * rcy[j].w)), t3);
            }
            acc += (t0 + t1) + (t2 + t3);
            dxs = dpp_mov<0x121>(dxs);   // row_ror:1
            dys = dpp_mov<0x121>(dys);
            acc = dpp_mov<0x121>(acc);
        }
        const int sw = lane ^ ((round & 1) ? 32 : 16);  // ^16,^32,^16,^32 -> home
        dxs = __shfl(dxs, sw);
        dys = __shfl(dys, sw);
        acc = __shfl(acc, sw);
    }

    out[p] = acc * EXP2F(f * (dx * dx + dy * dy));
}

extern "C" void kernel_launch(void* const* d_in, const int* in_sizes, int n_in,
                              void* d_out, int out_size, void* d_ws, size_t ws_size,
                              hipStream_t stream)
{
    const float* alphas  = (const float*)d_in[0];
    const float* betas   = (const float*)d_in[1];
    const float* K       = (const float*)d_in[2];
    const float* pixels  = (const float*)d_in[3];
    const float* centers = (const float*)d_in[4];
    const float* sdp2    = (const float*)d_in[5];
    float* outp          = (float*)d_out;
    float* ws            = (float*)d_ws;

    hipLaunchKernelGGL(prep_centers, dim3(NC / 256), dim3(256), 0, stream,
                       alphas, centers, sdp2, ws);
    hipLaunchKernelGGL(deform_k, dim3(BLOCKS_A), dim3(256), 0, stream,
                       betas, K, (float2*)(ws + WS_SXY_OFF));
    hipLaunchKernelGGL(rbf_k, dim3(NPIX / 256), dim3(256), 0, stream,
                       pixels, sdp2, ws, outp);
}

// Round 9
// 85.448 us; speedup vs baseline: 1.0044x; 1.0044x over previous
//
#include <hip/hip_runtime.h>

#if defined(__has_builtin)
#  if __has_builtin(__builtin_amdgcn_exp2f)
#    define EXP2F(x) __builtin_amdgcn_exp2f(x)
#  else
#    define EXP2F(x) exp2f(x)
#  endif
#else
#  define EXP2F(x) exp2f(x)
#endif

constexpr int NPIX  = 262144;
constexpr int NC    = 1024;
constexpr int NG    = 256;

// ---- DPP helpers (VALU pipe, no lgkm) ----
template <int CTRL>
__device__ __forceinline__ float dpp_add(float v) {
    union { float f; int i; } u, t;
    u.f = v;
    t.i = __builtin_amdgcn_update_dpp(0, u.i, CTRL, 0xF, 0xF, true);
    return v + t.f;
}
template <int CTRL>
__device__ __forceinline__ float dpp_mov(float v) {
    union { float f; int i; } u, t;
    u.f = v;
    t.i = __builtin_amdgcn_update_dpp(0, u.i, CTRL, 0xF, 0xF, true);
    return t.f;
}
__device__ __forceinline__ float sum16(float v) {
    v = dpp_add<0xB1>(v);   // quad_perm xor1
    v = dpp_add<0x4E>(v);   // quad_perm xor2
    v = dpp_add<0x141>(v);  // row_half_mirror (xor4 for sums)
    v = dpp_add<0x140>(v);  // row_mirror      (xor8 for sums)
    return v;               // all 16 lanes hold their 16-group total
}
// full-wave sum, result valid in lane 63 (bound_ctrl=1 zeros undefined sources)
__device__ __forceinline__ float sum64_lane63(float v) {
    v = sum16(v);
    v = dpp_add<0x142>(v);  // row_bcast15: lanes16-31 += R0 ; lanes48-63 += R2
    v = dpp_add<0x143>(v);  // row_bcast31: lanes32-63 += (R0+R1)
    return v;               // lane 63 = total
}
__device__ __forceinline__ float readlane63(float v) {
    union { float f; int i; } u; u.f = v;
    union { int i; float f; } r;
    r.i = __builtin_amdgcn_readlane(u.i, 63);
    return r.f;
}

// ws layout: cx[NC] | cy[NC] | ca[NC] | pad to 4096 | sxy[NPIX] (float2)
constexpr int WS_SXY_OFF = 4096;   // floats

// prep: SoA center pack (ca = alpha * 2^{f|c|^2})
__global__ void prep_centers(const float* __restrict__ alphas,
                             const float* __restrict__ centers,
                             const float* __restrict__ sdp2p,
                             float* __restrict__ ws)
{
    const int c = blockIdx.x * blockDim.x + threadIdx.x;
    if (c < NC) {
        const float f  = -1.44269504088896340736f / (2.0f * sdp2p[0]);
        const float cx = centers[2 * c + 0];
        const float cy = centers[2 * c + 1];
        ws[c]          = cx;
        ws[NC + c]     = cy;
        ws[2 * NC + c] = alphas[c] * EXP2F(f * (cx * cx + cy * cy));
    }
}

// ---- kernel A: s = K @ betas, pure streaming. ----
// One load = one full 1KB K row (64 lanes x float4, contiguous). Reduce on
// VALU only (DPP + readlane). 32 rows/wave, 2048 blocks -> 32 waves/CU.
constexpr int BLOCKS_A = NPIX / (4 * 32);   // 2048
__global__ __launch_bounds__(256, 8)        // cap VGPR at 64 -> 8 waves/SIMD
void deform_k(const float* __restrict__ betas,
              const float* __restrict__ K,
              float2* __restrict__ sxy)
{
    const int tid  = threadIdx.x;
    const int lane = tid & 63;
    const int wave = tid >> 6;

    // lane covers K cols 4*lane..4*lane+3 -> betas rows 4*lane..4*lane+3
    const float4* bf4 = (const float4*)betas;
    const float4 bb0 = bf4[2 * lane];       // rows 4l,4l+1 (x,y each)
    const float4 bb1 = bf4[2 * lane + 1];   // rows 4l+2,4l+3

    const int base = (blockIdx.x * 4 + wave) * 32;   // this wave's 32 rows
    const float* kbase = K + (size_t)base * NG;

    float ox = 0.f, oy = 0.f;               // owned row's sums (lanes 0..31)

    for (int it = 0; it < 32; it += 4) {
        float4 kv[4];
        #pragma unroll
        for (int j = 0; j < 4; ++j)
            kv[j] = ((const float4*)(kbase + (size_t)(it + j) * NG))[lane];
        #pragma unroll
        for (int j = 0; j < 4; ++j) {
            float sx = kv[j].x * bb0.x + kv[j].y * bb0.z;
            float sy = kv[j].x * bb0.y + kv[j].y * bb0.w;
            sx = fmaf(kv[j].z, bb1.x, sx);
            sy = fmaf(kv[j].z, bb1.y, sy);
            sx = fmaf(kv[j].w, bb1.z, sx);
            sy = fmaf(kv[j].w, bb1.w, sy);
            sx = sum64_lane63(sx);
            sy = sum64_lane63(sy);
            const float tx = readlane63(sx);   // uniform SGPR broadcast
            const float ty = readlane63(sy);
            if (lane == it + j) { ox = tx; oy = ty; }
        }
    }
    if (lane < 32) sxy[base + lane] = make_float2(ox, oy);
}

// ---- kernel B: RBF contraction, DPP-systolic over register-resident centers ----
__global__ __launch_bounds__(256, 4)
void rbf_k(const float* __restrict__ pixels,
           const float* __restrict__ sdp2p,
           const float* __restrict__ ws,
           float* __restrict__ out)
{
    const int tid  = threadIdx.x;
    const int lane = tid & 63;
    const int wave = tid >> 6;
    const int p    = blockIdx.x * 256 + wave * 64 + lane;

    const float f   = -1.44269504088896340736f / (2.0f * sdp2p[0]);
    const float m2f = -2.0f * f;

    // register-resident centers: lane holds c = lane*16 .. lane*16+15 (SoA)
    const float4* wcx4 = (const float4*)(ws);
    const float4* wcy4 = (const float4*)(ws + NC);
    const float4* wca4 = (const float4*)(ws + 2 * NC);
    float4 rcx[4], rcy[4], rca[4];
    #pragma unroll
    for (int j = 0; j < 4; ++j) {
        rcx[j] = wcx4[lane * 4 + j];
        rcy[j] = wcy4[lane * 4 + j];
        rca[j] = wca4[lane * 4 + j];
    }

    const float2 s  = ((const float2*)(ws + WS_SXY_OFF))[p];
    const float2 px = ((const float2*)pixels)[p];
    const float dx = px.x - s.x;
    const float dy = px.y - s.y;

    float dxs = m2f * dx, dys = m2f * dy, acc = 0.f;
    #pragma unroll 1
    for (int round = 0; round < 4; ++round) {
        #pragma unroll 2
        for (int t = 0; t < 16; ++t) {
            float t0 = 0.f, t1 = 0.f, t2 = 0.f, t3 = 0.f;
            #pragma unroll
            for (int j = 0; j < 4; ++j) {
                t0 = fmaf(rca[j].x, EXP2F(fmaf(dxs, rcx[j].x, dys * rcy[j].x)), t0);
                t1 = fmaf(rca[j].y, EXP2F(fmaf(dxs, rcx[j].y, dys * rcy[j].y)), t1);
                t2 = fmaf(rca[j].z, EXP2F(fmaf(dxs, rcx[j].z, dys * rcy[j].z)), t2);
                t3 = fmaf(rca[j].w, EXP2F(fmaf(dxs, rcx[j].w, dys * rcy[j].w)), t3);
            }
            acc += (t0 + t1) + (t2 + t3);
            dxs = dpp_mov<0x121>(dxs);   // row_ror:1
            dys = dpp_mov<0x121>(dys);
            acc = dpp_mov<0x121>(acc);
        }
        const int sw = lane ^ ((round & 1) ? 32 : 16);  // ^16,^32,^16,^32 -> home
        dxs = __shfl(dxs, sw);
        dys = __shfl(dys, sw);
        acc = __shfl(acc, sw);
    }

    out[p] = acc * EXP2F(f * (dx * dx + dy * dy));
}

extern "C" void kernel_launch(void* const* d_in, const int* in_sizes, int n_in,
                              void* d_out, int out_size, void* d_ws, size_t ws_size,
                              hipStream_t stream)
{
    const float* alphas  = (const float*)d_in[0];
    const float* betas   = (const float*)d_in[1];
    const float* K       = (const float*)d_in[2];
    const float* pixels  = (const float*)d_in[3];
    const float* centers = (const float*)d_in[4];
    const float* sdp2    = (const float*)d_in[5];
    float* outp          = (float*)d_out;
    float* ws            = (float*)d_ws;

    hipLaunchKernelGGL(prep_centers, dim3(NC / 256), dim3(256), 0, stream,
                       alphas, centers, sdp2, ws);
    hipLaunchKernelGGL(deform_k, dim3(BLOCKS_A), dim3(256), 0, stream,
                       betas, K, (float2*)(ws + WS_SXY_OFF));
    hipLaunchKernelGGL(rbf_k, dim3(NPIX / 256), dim3(256), 0, stream,
                       pixels, sdp2, ws, outp);
}

// Round 10
// 76.936 us; speedup vs baseline: 1.1155x; 1.1106x over previous
//
#include <hip/hip_runtime.h>

#if defined(__has_builtin)
#  if __has_builtin(__builtin_amdgcn_exp2f)
#    define EXP2F(x) __builtin_amdgcn_exp2f(x)
#  else
#    define EXP2F(x) exp2f(x)
#  endif
#else
#  define EXP2F(x) exp2f(x)
#endif

constexpr int NPIX  = 262144;
constexpr int NC    = 1024;
constexpr int NG    = 256;
constexpr int BLOCK = 256;                  // 4 waves; wave owns 128 px (2 chunks of 64)
constexpr int GRID  = NPIX / 512;           // 512 blocks

// ---- DPP helpers (VALU pipe, no lgkm) ----
template <int CTRL>
__device__ __forceinline__ float dpp_add(float v) {
    union { float f; int i; } u, t;
    u.f = v;
    t.i = __builtin_amdgcn_update_dpp(0, u.i, CTRL, 0xF, 0xF, true);
    return v + t.f;
}
template <int CTRL>
__device__ __forceinline__ float dpp_mov(float v) {
    union { float f; int i; } u, t;
    u.f = v;
    t.i = __builtin_amdgcn_update_dpp(0, u.i, CTRL, 0xF, 0xF, true);
    return t.f;
}
__device__ __forceinline__ float sum64_lane63(float v) {
    v = dpp_add<0xB1>(v);   // quad_perm xor1
    v = dpp_add<0x4E>(v);   // quad_perm xor2
    v = dpp_add<0x141>(v);  // row_half_mirror
    v = dpp_add<0x140>(v);  // row_mirror
    v = dpp_add<0x142>(v);  // row_bcast15
    v = dpp_add<0x143>(v);  // row_bcast31 -> lane 63 has wave total
    return v;
}
__device__ __forceinline__ float readlane63(float v) {
    union { float f; int i; } u; u.f = v;
    union { int i; float f; } r;
    r.i = __builtin_amdgcn_readlane(u.i, 63);
    return r.f;
}

__global__ __launch_bounds__(BLOCK, 4)
void kbpa_pipe(const float* __restrict__ alphas,
               const float* __restrict__ betas,
               const float* __restrict__ K,
               const float* __restrict__ pixels,
               const float* __restrict__ centers,
               const float* __restrict__ sdp2p,
               float* __restrict__ out)
{
    const int lane = threadIdx.x & 63;
    const int wave = threadIdx.x >> 6;

    const float f   = -1.44269504088896340736f / (2.0f * sdp2p[0]);
    const float m2f = -2.0f * f;

    // ---- register-resident centers: lane holds c = lane*16 .. +15 ----
    float4 rcx[4], rcy[4], rca[4];
    {
        const float4* c4 = (const float4*)centers;   // (x2i,y2i,x2i+1,y2i+1)
        const float4* a4 = (const float4*)alphas;
        #pragma unroll
        for (int j = 0; j < 4; ++j) {
            const float4 p0 = c4[lane * 8 + 2 * j];
            const float4 p1 = c4[lane * 8 + 2 * j + 1];
            rcx[j] = make_float4(p0.x, p0.z, p1.x, p1.z);
            rcy[j] = make_float4(p0.y, p0.w, p1.y, p1.w);
            const float4 al = a4[lane * 4 + j];
            rca[j].x = al.x * EXP2F(f * (rcx[j].x * rcx[j].x + rcy[j].x * rcy[j].x));
            rca[j].y = al.y * EXP2F(f * (rcx[j].y * rcx[j].y + rcy[j].y * rcy[j].y));
            rca[j].z = al.z * EXP2F(f * (rcx[j].z * rcx[j].z + rcy[j].z * rcy[j].z));
            rca[j].w = al.w * EXP2F(f * (rcx[j].w * rcx[j].w + rcy[j].w * rcy[j].w));
        }
    }

    // betas fragment: lane covers K cols 4l..4l+3 -> betas rows 4l..4l+3
    const float4* bf4 = (const float4*)betas;
    const float4 bb0 = bf4[2 * lane];
    const float4 bb1 = bf4[2 * lane + 1];

    const int w0 = blockIdx.x * 512 + wave * 128;    // chunk0 rows w0.., chunk1 w0+64..
    const float2 px0 = ((const float2*)pixels)[w0 + lane];
    const float2 px1 = ((const float2*)pixels)[w0 + 64 + lane];

    // ---- prologue: A(chunk0) — one load = one full 1KB K row ----
    float dx0 = 0.f, dy0 = 0.f;
    #pragma unroll 1
    for (int g = 0; g < 16; ++g) {
        float4 kv[4];
        #pragma unroll
        for (int j = 0; j < 4; ++j)
            kv[j] = ((const float4*)(K + (size_t)(w0 + g * 4 + j) * NG))[lane];
        #pragma unroll
        for (int j = 0; j < 4; ++j) {
            float sx = kv[j].x * bb0.x + kv[j].y * bb0.z;
            float sy = kv[j].x * bb0.y + kv[j].y * bb0.w;
            sx = fmaf(kv[j].z, bb1.x, sx); sy = fmaf(kv[j].z, bb1.y, sy);
            sx = fmaf(kv[j].w, bb1.z, sx); sy = fmaf(kv[j].w, bb1.w, sy);
            sx = sum64_lane63(sx); sy = sum64_lane63(sy);
            const float tx = readlane63(sx);
            const float ty = readlane63(sy);
            if (lane == g * 4 + j) { dx0 = px0.x - tx; dy0 = px0.y - ty; }
        }
    }

    // ---- steady: A(chunk1) loads in flight while B(chunk0) runs on VALU ----
    float dxs = m2f * dx0, dys = m2f * dy0, acc = 0.f;
    float dx1 = 0.f, dy1 = 0.f;
    #pragma unroll 1
    for (int g = 0; g < 16; ++g) {
        // issue 4 row loads (chunk1) — no use until the reduce below
        float4 kv[4];
        #pragma unroll
        for (int j = 0; j < 4; ++j)
            kv[j] = ((const float4*)(K + (size_t)(w0 + 64 + g * 4 + j) * NG))[lane];

        // 4 systolic B steps for chunk0 (pure VALU/trans + DPP, no memory)
        #pragma unroll
        for (int t = 0; t < 4; ++t) {
            float t0 = 0.f, t1 = 0.f, t2 = 0.f, t3 = 0.f;
            #pragma unroll
            for (int j = 0; j < 4; ++j) {
                t0 = fmaf(rca[j].x, EXP2F(fmaf(dxs, rcx[j].x, dys * rcy[j].x)), t0);
                t1 = fmaf(rca[j].y, EXP2F(fmaf(dxs, rcx[j].y, dys * rcy[j].y)), t1);
                t2 = fmaf(rca[j].z, EXP2F(fmaf(dxs, rcx[j].z, dys * rcy[j].z)), t2);
                t3 = fmaf(rca[j].w, EXP2F(fmaf(dxs, rcx[j].w, dys * rcy[j].w)), t3);
            }
            acc += (t0 + t1) + (t2 + t3);
            dxs = dpp_mov<0x121>(dxs);   // row_ror:1
            dys = dpp_mov<0x121>(dys);
            acc = dpp_mov<0x121>(acc);
        }
        if ((g & 3) == 3) {              // after steps 16/32/48/64: row swap
            const int sw = lane ^ (((g >> 2) & 1) ? 32 : 16);
            dxs = __shfl(dxs, sw);
            dys = __shfl(dys, sw);
            acc = __shfl(acc, sw);
        }

        // reduce the 4 loaded rows (vmcnt wait lands here, after the B steps)
        #pragma unroll
        for (int j = 0; j < 4; ++j) {
            float sx = kv[j].x * bb0.x + kv[j].y * bb0.z;
            float sy = kv[j].x * bb0.y + kv[j].y * bb0.w;
            sx = fmaf(kv[j].z, bb1.x, sx); sy = fmaf(kv[j].z, bb1.y, sy);
            sx = fmaf(kv[j].w, bb1.z, sx); sy = fmaf(kv[j].w, bb1.w, sy);
            sx = sum64_lane63(sx); sy = sum64_lane63(sy);
            const float tx = readlane63(sx);
            const float ty = readlane63(sy);
            if (lane == g * 4 + j) { dx1 = px1.x - tx; dy1 = px1.y - ty; }
        }
    }
    out[w0 + lane] = acc * EXP2F(f * (dx0 * dx0 + dy0 * dy0));

    // ---- epilogue: B(chunk1) ----
    float dxs1 = m2f * dx1, dys1 = m2f * dy1, acc1 = 0.f;
    #pragma unroll 1
    for (int round = 0; round < 4; ++round) {
        #pragma unroll 2
        for (int t = 0; t < 16; ++t) {
            float t0 = 0.f, t1 = 0.f, t2 = 0.f, t3 = 0.f;
            #pragma unroll
            for (int j = 0; j < 4; ++j) {
                t0 = fmaf(rca[j].x, EXP2F(fmaf(dxs1, rcx[j].x, dys1 * rcy[j].x)), t0);
                t1 = fmaf(rca[j].y, EXP2F(fmaf(dxs1, rcx[j].y, dys1 * rcy[j].y)), t1);
                t2 = fmaf(rca[j].z, EXP2F(fmaf(dxs1, rcx[j].z, dys1 * rcy[j].z)), t2);
                t3 = fmaf(rca[j].w, EXP2F(fmaf(dxs1, rcx[j].w, dys1 * rcy[j].w)), t3);
            }
            acc1 += (t0 + t1) + (t2 + t3);
            dxs1 = dpp_mov<0x121>(dxs1);
            dys1 = dpp_mov<0x121>(dys1);
            acc1 = dpp_mov<0x121>(acc1);
        }
        const int sw = lane ^ ((round & 1) ? 32 : 16);
        dxs1 = __shfl(dxs1, sw);
        dys1 = __shfl(dys1, sw);
        acc1 = __shfl(acc1, sw);
    }
    out[w0 + 64 + lane] = acc1 * EXP2F(f * (dx1 * dx1 + dy1 * dy1));
}

extern "C" void kernel_launch(void* const* d_in, const int* in_sizes, int n_in,
                              void* d_out, int out_size, void* d_ws, size_t ws_size,
                              hipStream_t stream)
{
    const float* alphas  = (const float*)d_in[0];
    const float* betas   = (const float*)d_in[1];
    const float* K       = (const float*)d_in[2];
    const float* pixels  = (const float*)d_in[3];
    const float* centers = (const float*)d_in[4];
    const float* sdp2    = (const float*)d_in[5];
    float* outp          = (float*)d_out;

    hipLaunchKernelGGL(kbpa_pipe, dim3(GRID), dim3(BLOCK), 0, stream,
                       alphas, betas, K, pixels, centers, sdp2, outp);
}

// Round 11
// 72.436 us; speedup vs baseline: 1.1849x; 1.0621x over previous
//
#include <hip/hip_runtime.h>

#if defined(__has_builtin)
#  if __has_builtin(__builtin_amdgcn_exp2f)
#    define EXP2F(x) __builtin_amdgcn_exp2f(x)
#  else
#    define EXP2F(x) exp2f(x)
#  endif
#else
#  define EXP2F(x) exp2f(x)
#endif

constexpr int NPIX  = 262144;
constexpr int NC    = 1024;
constexpr int NG    = 256;
constexpr int BLOCK = 256;                  // 4 waves; wave owns 128 px (2 chunks of 64)
constexpr int GRID  = NPIX / 512;           // 512 blocks

// ---- DPP helpers (VALU pipe, no lgkm) ----
template <int CTRL>
__device__ __forceinline__ float dpp_add(float v) {
    union { float f; int i; } u, t;
    u.f = v;
    t.i = __builtin_amdgcn_update_dpp(0, u.i, CTRL, 0xF, 0xF, true);
    return v + t.f;
}
template <int CTRL>
__device__ __forceinline__ float dpp_mov(float v) {
    union { float f; int i; } u, t;
    u.f = v;
    t.i = __builtin_amdgcn_update_dpp(0, u.i, CTRL, 0xF, 0xF, true);
    return t.f;
}
__device__ __forceinline__ float sum64_lane63(float v) {
    v = dpp_add<0xB1>(v);   // quad_perm xor1
    v = dpp_add<0x4E>(v);   // quad_perm xor2
    v = dpp_add<0x141>(v);  // row_half_mirror
    v = dpp_add<0x140>(v);  // row_mirror
    v = dpp_add<0x142>(v);  // row_bcast15
    v = dpp_add<0x143>(v);  // row_bcast31 -> lane 63 has wave total
    return v;
}
__device__ __forceinline__ float readlane63(float v) {
    union { float f; int i; } u; u.f = v;
    union { int i; float f; } r;
    r.i = __builtin_amdgcn_readlane(u.i, 63);
    return r.f;
}

// 4 coalesced full-row loads (1KB each) into a statically-named buffer
#define LOAD4(BUF, ABSROW)                                                   \
    _Pragma("unroll")                                                        \
    for (int j = 0; j < 4; ++j)                                              \
        BUF[j] = ((const float4*)(K + (size_t)((ABSROW) + j) * NG))[lane];

// reduce 4 buffered rows -> owner lanes capture (dx,dy)
#define RED4(BUF, REL, PX, DXO, DYO)                                         \
    _Pragma("unroll")                                                        \
    for (int j = 0; j < 4; ++j) {                                            \
        float sx = BUF[j].x * bb0.x + BUF[j].y * bb0.z;                      \
        float sy = BUF[j].x * bb0.y + BUF[j].y * bb0.w;                      \
        sx = fmaf(BUF[j].z, bb1.x, sx); sy = fmaf(BUF[j].z, bb1.y, sy);      \
        sx = fmaf(BUF[j].w, bb1.z, sx); sy = fmaf(BUF[j].w, bb1.w, sy);      \
        sx = sum64_lane63(sx); sy = sum64_lane63(sy);                        \
        const float tx = readlane63(sx);                                     \
        const float ty = readlane63(sy);                                     \
        if (lane == (REL) + j) { DXO = PX.x - tx; DYO = PX.y - ty; }         \
    }

// N systolic B steps on state (dxs, dys, acc) — pure VALU/trans + DPP
#define BSTEPS(N)                                                            \
    _Pragma("unroll")                                                        \
    for (int t = 0; t < (N); ++t) {                                          \
        float t0 = 0.f, t1 = 0.f, t2 = 0.f, t3 = 0.f;                        \
        _Pragma("unroll")                                                    \
        for (int j = 0; j < 4; ++j) {                                        \
            t0 = fmaf(rca[j].x, EXP2F(fmaf(dxs, rcx[j].x, dys * rcy[j].x)), t0); \
            t1 = fmaf(rca[j].y, EXP2F(fmaf(dxs, rcx[j].y, dys * rcy[j].y)), t1); \
            t2 = fmaf(rca[j].z, EXP2F(fmaf(dxs, rcx[j].z, dys * rcy[j].z)), t2); \
            t3 = fmaf(rca[j].w, EXP2F(fmaf(dxs, rcx[j].w, dys * rcy[j].w)), t3); \
        }                                                                    \
        acc += (t0 + t1) + (t2 + t3);                                        \
        dxs = dpp_mov<0x121>(dxs);   /* row_ror:1 */                         \
        dys = dpp_mov<0x121>(dys);                                           \
        acc = dpp_mov<0x121>(acc);                                           \
    }

__global__ __launch_bounds__(BLOCK, 2)
void kbpa_pipe(const float* __restrict__ alphas,
               const float* __restrict__ betas,
               const float* __restrict__ K,
               const float* __restrict__ pixels,
               const float* __restrict__ centers,
               const float* __restrict__ sdp2p,
               float* __restrict__ out)
{
    const int lane = threadIdx.x & 63;
    const int wave = threadIdx.x >> 6;

    // bijective XCD swizzle (gridDim.x = 512, divisible by 8)
    const int cpx = GRID / 8;
    const int bid = (blockIdx.x & 7) * cpx + (blockIdx.x >> 3);

    const float f   = -1.44269504088896340736f / (2.0f * sdp2p[0]);
    const float m2f = -2.0f * f;

    // ---- register-resident centers: lane holds c = lane*16 .. +15 ----
    float4 rcx[4], rcy[4], rca[4];
    {
        const float4* c4 = (const float4*)centers;
        const float4* a4 = (const float4*)alphas;
        #pragma unroll
        for (int j = 0; j < 4; ++j) {
            const float4 p0 = c4[lane * 8 + 2 * j];
            const float4 p1 = c4[lane * 8 + 2 * j + 1];
            rcx[j] = make_float4(p0.x, p0.z, p1.x, p1.z);
            rcy[j] = make_float4(p0.y, p0.w, p1.y, p1.w);
            const float4 al = a4[lane * 4 + j];
            rca[j].x = al.x * EXP2F(f * (rcx[j].x * rcx[j].x + rcy[j].x * rcy[j].x));
            rca[j].y = al.y * EXP2F(f * (rcx[j].y * rcx[j].y + rcy[j].y * rcy[j].y));
            rca[j].z = al.z * EXP2F(f * (rcx[j].z * rcx[j].z + rcy[j].z * rcy[j].z));
            rca[j].w = al.w * EXP2F(f * (rcx[j].w * rcx[j].w + rcy[j].w * rcy[j].w));
        }
    }

    // betas fragment: lane covers K cols 4l..4l+3 -> betas rows 4l..4l+3
    const float4* bf4 = (const float4*)betas;
    const float4 bb0 = bf4[2 * lane];
    const float4 bb1 = bf4[2 * lane + 1];

    const int w0 = bid * 512 + wave * 128;       // chunk0: w0.., chunk1: w0+64..
    const int w1 = w0 + 64;
    const float2 px0 = ((const float2*)pixels)[w0 + lane];
    const float2 px1 = ((const float2*)pixels)[w1 + lane];

    float dx0 = 0.f, dy0 = 0.f, dx1 = 0.f, dy1 = 0.f;
    float4 kva[4], kvb[4];

    // ---- prologue: A(chunk0), double-buffered (>=4 loads always in flight) ----
    LOAD4(kva, w0 + 0)
    #pragma unroll 1
    for (int gg = 0; gg < 8; ++gg) {
        const int g = 2 * gg;
        LOAD4(kvb, w0 + (g + 1) * 4)
        RED4(kva, g * 4, px0, dx0, dy0)
        if (gg < 7) { LOAD4(kva, w0 + (g + 2) * 4) }
        RED4(kvb, (g + 1) * 4, px0, dx0, dy0)
    }

    // ---- steady: A(chunk1) streams (double-buffered) while B(chunk0) on VALU ----
    float dxs = m2f * dx0, dys = m2f * dy0, acc = 0.f;
    LOAD4(kva, w1 + 0)
    #pragma unroll 1
    for (int gg = 0; gg < 8; ++gg) {
        const int g = 2 * gg;
        LOAD4(kvb, w1 + (g + 1) * 4)
        BSTEPS(4)
        RED4(kva, g * 4, px1, dx1, dy1)
        if (gg < 7) { LOAD4(kva, w1 + (g + 2) * 4) }
        BSTEPS(4)
        RED4(kvb, (g + 1) * 4, px1, dx1, dy1)
        if (gg & 1) {                       // after t = 16,32,48,64: row swap
            const int sw = lane ^ ((gg & 2) ? 32 : 16);
            dxs = __shfl(dxs, sw);
            dys = __shfl(dys, sw);
            acc = __shfl(acc, sw);
        }
    }
    out[w0 + lane] = acc * EXP2F(f * (dx0 * dx0 + dy0 * dy0));

    // ---- epilogue: B(chunk1) ----
    dxs = m2f * dx1; dys = m2f * dy1; acc = 0.f;
    #pragma unroll 1
    for (int round = 0; round < 4; ++round) {
        BSTEPS(16)
        const int sw = lane ^ ((round & 1) ? 32 : 16);
        dxs = __shfl(dxs, sw);
        dys = __shfl(dys, sw);
        acc = __shfl(acc, sw);
    }
    out[w1 + lane] = acc * EXP2F(f * (dx1 * dx1 + dy1 * dy1));
}

extern "C" void kernel_launch(void* const* d_in, const int* in_sizes, int n_in,
                              void* d_out, int out_size, void* d_ws, size_t ws_size,
                              hipStream_t stream)
{
    const float* alphas  = (const float*)d_in[0];
    const float* betas   = (const float*)d_in[1];
    const float* K       = (const float*)d_in[2];
    const float* pixels  = (const float*)d_in[3];
    const float* centers = (const float*)d_in[4];
    const float* sdp2    = (const float*)d_in[5];
    float* outp          = (float*)d_out;

    hipLaunchKernelGGL(kbpa_pipe, dim3(GRID), dim3(BLOCK), 0, stream,
                       alphas, betas, K, pixels, centers, sdp2, outp);
}